// Round 1
// baseline (272.147 us; speedup 1.0000x reference)
//
#include <hip/hip_runtime.h>

#define B 8
#define N 8192
#define M 2048
#define NITER 4
#define BASE_ALPHA 0.1f

// ws layout (bytes):
//   pack : float4[B*M]     @ 0         (262144)   {y0,y1,y2, y0^2+y1^2+y2^2}
//   ref4 : float4[B*N]     @ 262144    (1048576)  {rx,ry,rz, min_dist}
//   idxb : int[B*N]        @ 1310720   (262144)
//   maxb : uint[NITER*B]   @ 1572864   (128)
#define OFF_REF4 262144
#define OFF_IDX  1310720
#define OFF_MAX  1572864

__global__ __launch_bounds__(256) void init_kernel(const float* __restrict__ partial,
                                                   float4* __restrict__ pack,
                                                   unsigned int* __restrict__ maxb) {
    int t = blockIdx.x * 256 + threadIdx.x;
    if (t < NITER * B) maxb[t] = 0u;
    if (t < B * M) {
        float y0 = partial[t * 3 + 0];
        float y1 = partial[t * 3 + 1];
        float y2 = partial[t * 3 + 2];
        pack[t] = make_float4(y0, y1, y2, y0 * y0 + y1 * y1 + y2 * y2);
    }
}

__global__ __launch_bounds__(256) void iter_kernel(const float* __restrict__ pred,
                                                   const float4* __restrict__ pack,
                                                   float4* __restrict__ ref4,
                                                   int* __restrict__ idxb,
                                                   unsigned int* __restrict__ maxb,
                                                   int iter) {
    __shared__ float4 tile[M];   // 32 KB
    const int b = blockIdx.x >> 5;        // 32 blocks per batch
    const int chunk = blockIdx.x & 31;
    const int n = chunk * 256 + threadIdx.x;
    const int p = b * N + n;

    const float4* pb = pack + b * M;
    for (int j = threadIdx.x; j < M; j += 256) tile[j] = pb[j];

    // apply previous iteration's update (or load pred at iter 0)
    float rx, ry, rz;
    if (iter == 0) {
        rx = pred[p * 3 + 0];
        ry = pred[p * 3 + 1];
        rz = pred[p * 3 + 2];
    } else {
        float4 f = ref4[p];
        int id = idxb[p];
        float mx = __uint_as_float(maxb[(iter - 1) * B + b]);
        float4 nr = pb[id];
        float inv = 1.0f / (mx + 1e-6f);
        float alpha = BASE_ALPHA * (2.0f - f.w * inv);
        rx = fmaf(alpha, nr.x - f.x, f.x);
        ry = fmaf(alpha, nr.y - f.y, f.y);
        rz = fmaf(alpha, nr.z - f.z, f.z);
    }
    __syncthreads();

    const float nx0 = -2.0f * rx, nx1 = -2.0f * ry, nx2 = -2.0f * rz;
    const float x2 = rx * rx + ry * ry + rz * rz;

    // argmin over t_j = ||y_j||^2 - 2 x.y_j  (== d^2 - ||x||^2, same argmin)
    float v0 = 3.402823466e+38f, v1 = v0, v2 = v0, v3 = v0;
    int i0 = 0, i1 = 0, i2 = 0, i3 = 0;
    for (int j = 0; j < M; j += 4) {
        float4 q0 = tile[j + 0];
        float4 q1 = tile[j + 1];
        float4 q2 = tile[j + 2];
        float4 q3 = tile[j + 3];
        float t0 = fmaf(nx0, q0.x, fmaf(nx1, q0.y, fmaf(nx2, q0.z, q0.w)));
        float t1 = fmaf(nx0, q1.x, fmaf(nx1, q1.y, fmaf(nx2, q1.z, q1.w)));
        float t2 = fmaf(nx0, q2.x, fmaf(nx1, q2.y, fmaf(nx2, q2.z, q2.w)));
        float t3 = fmaf(nx0, q3.x, fmaf(nx1, q3.y, fmaf(nx2, q3.z, q3.w)));
        if (t0 < v0) { v0 = t0; i0 = j + 0; }
        if (t1 < v1) { v1 = t1; i1 = j + 1; }
        if (t2 < v2) { v2 = t2; i2 = j + 2; }
        if (t3 < v3) { v3 = t3; i3 = j + 3; }
    }
    // combine, tie-break to lowest index (matches jnp.argmin first-occurrence)
    float bv = v0; int bi = i0;
    if (v1 < bv || (v1 == bv && i1 < bi)) { bv = v1; bi = i1; }
    if (v2 < bv || (v2 == bv && i2 < bi)) { bv = v2; bi = i2; }
    if (v3 < bv || (v3 == bv && i3 < bi)) { bv = v3; bi = i3; }

    float md = sqrtf(fmaxf(x2 + bv, 0.0f));
    ref4[p] = make_float4(rx, ry, rz, md);
    idxb[p] = bi;

    // per-wave max reduction, then one atomic per wave
    float wm = md;
    for (int o = 32; o > 0; o >>= 1) wm = fmaxf(wm, __shfl_down(wm, o));
    if ((threadIdx.x & 63) == 0)
        atomicMax(&maxb[iter * B + b], __float_as_uint(wm));  // md >= 0: uint order == float order
}

__global__ __launch_bounds__(256) void final_kernel(const float4* __restrict__ pack,
                                                    const float4* __restrict__ ref4,
                                                    const int* __restrict__ idxb,
                                                    const unsigned int* __restrict__ maxb,
                                                    float* __restrict__ out) {
    int p = blockIdx.x * 256 + threadIdx.x;   // B*N threads
    int b = p >> 13;                          // N = 8192
    float4 f = ref4[p];
    int id = idxb[p];
    float mx = __uint_as_float(maxb[(NITER - 1) * B + b]);
    float4 nr = pack[b * M + id];
    float inv = 1.0f / (mx + 1e-6f);
    float alpha = BASE_ALPHA * (2.0f - f.w * inv);
    out[p * 3 + 0] = fmaf(alpha, nr.x - f.x, f.x);
    out[p * 3 + 1] = fmaf(alpha, nr.y - f.y, f.y);
    out[p * 3 + 2] = fmaf(alpha, nr.z - f.z, f.z);
}

extern "C" void kernel_launch(void* const* d_in, const int* in_sizes, int n_in,
                              void* d_out, int out_size, void* d_ws, size_t ws_size,
                              hipStream_t stream) {
    const float* pred = (const float*)d_in[0];
    const float* partial = (const float*)d_in[1];
    char* ws = (char*)d_ws;
    float4* pack = (float4*)ws;
    float4* ref4 = (float4*)(ws + OFF_REF4);
    int* idxb = (int*)(ws + OFF_IDX);
    unsigned int* maxb = (unsigned int*)(ws + OFF_MAX);
    float* out = (float*)d_out;

    hipLaunchKernelGGL(init_kernel, dim3(64), dim3(256), 0, stream, partial, pack, maxb);
    for (int it = 0; it < NITER; ++it)
        hipLaunchKernelGGL(iter_kernel, dim3(B * (N / 256)), dim3(256), 0, stream,
                           pred, pack, ref4, idxb, maxb, it);
    hipLaunchKernelGGL(final_kernel, dim3(B * N / 256), dim3(256), 0, stream,
                       pack, ref4, idxb, maxb, out);
}

// Round 2
// 239.683 us; speedup vs baseline: 1.1354x; 1.1354x over previous
//
#include <hip/hip_runtime.h>

#define B 8
#define N 8192
#define M 2048
#define NITER 4
#define BASE_ALPHA 0.1f
#define P 8                    // points per thread
#define SPLITS 16              // j-dimension split
#define JS (M / SPLITS)        // 128 y-points per block
#define CHUNK (256 * P)        // 2048 points per block
#define NCHUNK ((B * N) / CHUNK) // 32
#define TOTPTS (B * N)         // 65536

// ws layout (bytes):
//   pack   : float4[B*M]   @ 0        (262144)  {y0,y1,y2, |y|^2}
//   state  : float4[B*N]   @ 262144   (1048576) {x,y,z, min_dist} of prev iter
//   newpos : float4[B*N]   @ 1310720  (1048576) {x,y,z, |r|^2} current refined
//   idxb   : int[B*N]      @ 2359296  (262144)
//   keys   : u64[B*N]      @ 2621440  (524288)  packed (ordered_t, idx), atomicMin
//   maxb   : uint[NITER*B] @ 3145728  (128)
#define OFF_STATE  262144
#define OFF_NEWPOS 1310720
#define OFF_IDX    2359296
#define OFF_KEYS   2621440
#define OFF_MAX    3145728

__device__ __forceinline__ unsigned long long enc_key(float t, int idx) {
    unsigned int b = __float_as_uint(t);
    b ^= (b & 0x80000000u) ? 0xFFFFFFFFu : 0x80000000u;   // float order -> uint order
    return (((unsigned long long)b) << 32) | (unsigned int)idx;
}
__device__ __forceinline__ float dec_val(unsigned long long k) {
    unsigned int b = (unsigned int)(k >> 32);
    b = (b & 0x80000000u) ? (b ^ 0x80000000u) : ~b;
    return __uint_as_float(b);
}

__global__ __launch_bounds__(256) void init_kernel(const float* __restrict__ partial,
                                                   float4* __restrict__ pack,
                                                   unsigned long long* __restrict__ keys,
                                                   unsigned int* __restrict__ maxb) {
    int t = blockIdx.x * 256 + threadIdx.x;   // 65536 threads
    keys[t] = ~0ull;
    if (t < NITER * B) maxb[t] = 0u;
    if (t < B * M) {
        float y0 = partial[t * 3 + 0];
        float y1 = partial[t * 3 + 1];
        float y2 = partial[t * 3 + 2];
        pack[t] = make_float4(y0, y1, y2, y0 * y0 + y1 * y1 + y2 * y2);
    }
}

// One block: 2048 consecutive points (P=8 per thread) x 128 y-points (one split).
// Computes partial argmin of t_j = |y|^2 - 2 x.y and folds via u64 atomicMin.
__global__ __launch_bounds__(256) void pass1(const float* __restrict__ pred,
                                             const float4* __restrict__ pack,
                                             const float4* __restrict__ state,
                                             const int* __restrict__ idxb,
                                             const unsigned int* __restrict__ maxb,
                                             float4* __restrict__ newpos,
                                             unsigned long long* __restrict__ keys,
                                             int iter) {
    const int split = blockIdx.x & (SPLITS - 1);
    const int chunk = blockIdx.x >> 4;
    const int pbase = chunk * CHUNK + threadIdx.x;
    const int b = (chunk * CHUNK) >> 13;          // 8192 points per batch
    const float4* __restrict__ pb = pack + b * M;

    // recompute refined positions from prev-iter state (redundant across splits, cheap)
    float nx0[P], nx1[P], nx2[P];
    if (iter == 0) {
        #pragma unroll
        for (int k = 0; k < P; ++k) {
            int p = pbase + k * 256;
            float rx = pred[p * 3 + 0];
            float ry = pred[p * 3 + 1];
            float rz = pred[p * 3 + 2];
            if (split == 0) newpos[p] = make_float4(rx, ry, rz, rx * rx + ry * ry + rz * rz);
            nx0[k] = -2.0f * rx; nx1[k] = -2.0f * ry; nx2[k] = -2.0f * rz;
        }
    } else {
        float mx = __uint_as_float(maxb[(iter - 1) * B + b]);
        float inv = 1.0f / (mx + 1e-6f);
        #pragma unroll
        for (int k = 0; k < P; ++k) {
            int p = pbase + k * 256;
            float4 f = state[p];
            float4 nr = pb[idxb[p]];
            float alpha = BASE_ALPHA * (2.0f - f.w * inv);
            float rx = fmaf(alpha, nr.x - f.x, f.x);
            float ry = fmaf(alpha, nr.y - f.y, f.y);
            float rz = fmaf(alpha, nr.z - f.z, f.z);
            if (split == 0) newpos[p] = make_float4(rx, ry, rz, rx * rx + ry * ry + rz * rz);
            nx0[k] = -2.0f * rx; nx1[k] = -2.0f * ry; nx2[k] = -2.0f * rz;
        }
    }

    float vb[P]; int ib[P];
    #pragma unroll
    for (int k = 0; k < P; ++k) { vb[k] = 3.402823466e+38f; ib[k] = 0; }

    // wave-uniform address stream -> scalar loads (s_load_dwordx4), no LDS
    const float4* __restrict__ pj = pb + split * JS;
    #pragma unroll 4
    for (int j = 0; j < JS; ++j) {
        float4 q = pj[j];
        #pragma unroll
        for (int k = 0; k < P; ++k) {
            float t = fmaf(nx0[k], q.x, fmaf(nx1[k], q.y, fmaf(nx2[k], q.z, q.w)));
            if (t < vb[k]) { vb[k] = t; ib[k] = j; }   // strict < keeps earliest j
        }
    }

    #pragma unroll
    for (int k = 0; k < P; ++k) {
        int p = pbase + k * 256;
        atomicMin(&keys[p], enc_key(vb[k], split * JS + ib[k]));
    }
}

__global__ __launch_bounds__(256) void combine(const float4* __restrict__ newpos,
                                               unsigned long long* __restrict__ keys,
                                               float4* __restrict__ state,
                                               int* __restrict__ idxb,
                                               unsigned int* __restrict__ maxb,
                                               int iter) {
    int p = blockIdx.x * 256 + threadIdx.x;   // 65536 threads
    int b = p >> 13;
    unsigned long long k = keys[p];
    keys[p] = ~0ull;                          // re-arm for next iteration's pass1
    float t = dec_val(k);
    int id = (int)(k & 0xFFFFFFFFull);
    float4 np = newpos[p];
    float md = sqrtf(fmaxf(np.w + t, 0.0f));  // |r|^2 + (|y|^2 - 2 r.y)
    state[p] = make_float4(np.x, np.y, np.z, md);
    idxb[p] = id;
    float wm = md;
    for (int o = 32; o > 0; o >>= 1) wm = fmaxf(wm, __shfl_down(wm, o));
    if ((threadIdx.x & 63) == 0)
        atomicMax(&maxb[iter * B + b], __float_as_uint(wm));  // md >= 0
}

__global__ __launch_bounds__(256) void final_kernel(const float4* __restrict__ pack,
                                                    const float4* __restrict__ state,
                                                    const int* __restrict__ idxb,
                                                    const unsigned int* __restrict__ maxb,
                                                    float* __restrict__ out) {
    int p = blockIdx.x * 256 + threadIdx.x;
    int b = p >> 13;
    float4 f = state[p];
    int id = idxb[p];
    float mx = __uint_as_float(maxb[(NITER - 1) * B + b]);
    float4 nr = pack[b * M + id];
    float inv = 1.0f / (mx + 1e-6f);
    float alpha = BASE_ALPHA * (2.0f - f.w * inv);
    out[p * 3 + 0] = fmaf(alpha, nr.x - f.x, f.x);
    out[p * 3 + 1] = fmaf(alpha, nr.y - f.y, f.y);
    out[p * 3 + 2] = fmaf(alpha, nr.z - f.z, f.z);
}

extern "C" void kernel_launch(void* const* d_in, const int* in_sizes, int n_in,
                              void* d_out, int out_size, void* d_ws, size_t ws_size,
                              hipStream_t stream) {
    const float* pred = (const float*)d_in[0];
    const float* partial = (const float*)d_in[1];
    char* ws = (char*)d_ws;
    float4* pack = (float4*)ws;
    float4* state = (float4*)(ws + OFF_STATE);
    float4* newpos = (float4*)(ws + OFF_NEWPOS);
    int* idxb = (int*)(ws + OFF_IDX);
    unsigned long long* keys = (unsigned long long*)(ws + OFF_KEYS);
    unsigned int* maxb = (unsigned int*)(ws + OFF_MAX);
    float* out = (float*)d_out;

    hipLaunchKernelGGL(init_kernel, dim3(TOTPTS / 256), dim3(256), 0, stream,
                       partial, pack, keys, maxb);
    for (int it = 0; it < NITER; ++it) {
        hipLaunchKernelGGL(pass1, dim3(NCHUNK * SPLITS), dim3(256), 0, stream,
                           pred, pack, state, idxb, maxb, newpos, keys, it);
        hipLaunchKernelGGL(combine, dim3(TOTPTS / 256), dim3(256), 0, stream,
                           newpos, keys, state, idxb, maxb, it);
    }
    hipLaunchKernelGGL(final_kernel, dim3(TOTPTS / 256), dim3(256), 0, stream,
                       pack, state, idxb, maxb, out);
}